// Round 19
// baseline (55.511 us; speedup 1.0000x reference)
//
#include <hip/hip_runtime.h>
#include <cstdint>

#define P_ 12
#define B_ 32
#define V_ 32
#define F_ 256
#define S_ 32
#define NL_ 16
#define LF_ 64
#define T_ 20
#define H_ 8
#define D_ 32
#define L_ 512

typedef short bf16x8 __attribute__((ext_vector_type(8)));
typedef short bf16x4 __attribute__((ext_vector_type(4)));
typedef float f32x4 __attribute__((ext_vector_type(4)));

static __device__ __forceinline__ short f2bf(float f) {
  uint32_t u = __builtin_bit_cast(uint32_t, f);
  uint32_t r = u + 0x7FFFu + ((u >> 16) & 1u);  // RNE
  return (short)(r >> 16);
}

// packed f32x2 -> bf16x2 (RNE), 1 VALU op
static __device__ __forceinline__ uint32_t cvtpk(float lo, float hi) {
  uint32_t r;
  asm("v_cvt_pk_bf16_f32 %0, %1, %2" : "=v"(r) : "v"(lo), "v"(hi));
  return r;
}
static __device__ __forceinline__ bf16x8 pack8(uint32_t d0, uint32_t d1,
                                               uint32_t d2, uint32_t d3) {
  uint4 u = {d0, d1, d2, d3};
  return __builtin_bit_cast(bf16x8, u);
}
static __device__ __forceinline__ bf16x4 pack4(uint32_t d0, uint32_t d1) {
  uint2 u = {d0, d1};
  return __builtin_bit_cast(bf16x4, u);
}
static __device__ __forceinline__ float vexp2(float x) {
  float y;
  asm("v_exp_f32 %0, %1" : "=v"(y) : "v"(x));
  return y;
}
static __device__ __forceinline__ float vlog2(float x) {
  float y;
  asm("v_log_f32 %0, %1" : "=v"(y) : "v"(x));
  return y;
}

#define L2E 1.4426950408889634f
#define LN2 0.6931471805599453f

// ---------------------------------------------------------------------------
// Kernel P: prep = weight transpose/convert + mask precompute.
// ---------------------------------------------------------------------------
__global__ __launch_bounds__(256) void prep_kernel(
    const float* __restrict__ Wk, const float* __restrict__ Wv,
    const float* __restrict__ Wc,
    const int* __restrict__ mask_input, const int* __restrict__ mask_lanes,
    short* __restrict__ WkT, short* __restrict__ WvT, short* __restrict__ WcT,
    unsigned int* __restrict__ maskr, int* __restrict__ mi) {
  int t = blockIdx.x * 256 + threadIdx.x;
  if (t < 2048) {                 // WkT
    int f = t >> 3, k0 = (t & 7) * 8;
    bf16x8 o;
#pragma unroll
    for (int e = 0; e < 8; ++e) o[e] = f2bf(Wk[(k0 + e) * F_ + f]);
    *(bf16x8*)&WkT[f * LF_ + k0] = o;
  } else if (t < 4096) {          // WvT
    int i = t - 2048;
    int f = i >> 3, k0 = (i & 7) * 8;
    bf16x8 o;
#pragma unroll
    for (int e = 0; e < 8; ++e) o[e] = f2bf(Wv[(k0 + e) * F_ + f]);
    *(bf16x8*)&WvT[f * LF_ + k0] = o;
  } else if (t < 12288) {         // WcT
    int i = t - 4096;
    int f = i >> 5, k0 = (i & 31) * 8;
    bf16x8 o;
#pragma unroll
    for (int e = 0; e < 8; ++e) o[e] = f2bf(Wc[(k0 + e) * F_ + f]);
    *(bf16x8*)&WcT[f * F_ + k0] = o;
  } else if (t < 12800) {         // maskr: word = l&15, bit = l>>4
    int i = t - 12288;
    int b = i >> 4, r = i & 15;
    unsigned int bits = 0u;
    for (int lt = 0; lt < 32; ++lt)
      if (mask_lanes[(lt * B_ + b) * NL_ + r]) bits |= (1u << lt);
    maskr[i] = bits;
  } else if (t < 13824) {         // mi
    int i = t - 12800;
    int b = i >> 5, v = i & 31;
    int any = 0;
    for (int tt = 0; tt < T_; ++tt) any |= mask_input[(tt * B_ + b) * V_ + v];
    mi[i] = any ? 1 : 0;
  }
}

// Stage tiles [T0,T1) (16 rows each) strided over the 12 waves:
// projects K (sigma-permuted rows) and log_sigmoid(V) (transposed) into LDS.
#define STAGE_RANGE(T0, T1)                                                   \
  for (int t = (T0) + w; t < (T1); t += 12) {                                 \
    int l0 = t * 16;                                                          \
    int l = l0 + r;                                                           \
    int nl = l >> 5, s = l & 31;                                              \
    const float* xrow = &lanes[((s * B_ + b) * NL_ + nl) * LF_];              \
    bf16x8 xf[2];                                                             \
    _Pragma("unroll") for (int c = 0; c < 2; ++c) {                           \
      float4 a = *(const float4*)&xrow[c * 32 + g * 8];                       \
      float4 q = *(const float4*)&xrow[c * 32 + g * 8 + 4];                   \
      xf[c] = pack8(cvtpk(a.x, a.y), cvtpk(a.z, a.w),                         \
                    cvtpk(q.x, q.y), cvtpk(q.z, q.w));                        \
    }                                                                         \
    int sl = (l & ~31) | (((l >> 2) & 1) << 4) | (((l >> 3) & 3) << 2) |      \
             (l & 3);                                                         \
    _Pragma("unroll") for (int dt = 0; dt < 2; ++dt) {                        \
      f32x4 aK = __builtin_amdgcn_mfma_f32_16x16x32_bf16(wk[dt][0], xf[0],    \
                                                         zero, 0, 0, 0);      \
      aK = __builtin_amdgcn_mfma_f32_16x16x32_bf16(wk[dt][1], xf[1], aK, 0,   \
                                                   0, 0);                     \
      *(bf16x4*)&Ks[sl * 40 + dt * 16 + g * 4] =                              \
          pack4(cvtpk(aK[0] + bk4[dt].x, aK[1] + bk4[dt].y),                  \
                cvtpk(aK[2] + bk4[dt].z, aK[3] + bk4[dt].w));                 \
      f32x4 aV = __builtin_amdgcn_mfma_f32_16x16x32_bf16(xf[0], wv[dt][0],    \
                                                         zero, 0, 0, 0);      \
      aV = __builtin_amdgcn_mfma_f32_16x16x32_bf16(xf[1], wv[dt][1], aV, 0,   \
                                                   0, 0);                     \
      float ls[4];                                                            \
      _Pragma("unroll") for (int reg = 0; reg < 4; ++reg) {                   \
        float x = aV[reg] + bvf[dt];                                          \
        float z = vexp2(fabsf(x) * -L2E);                                     \
        ls[reg] = fminf(x, 0.f) - vlog2(1.f + z) * LN2;                       \
      }                                                                       \
      *(bf16x4*)&Vt[(dt * 16 + r) * 520 + l0 + g * 4] =                       \
          pack4(cvtpk(ls[0], ls[1]), cvtpk(ls[2], ls[3]));                    \
    }                                                                         \
  }

// One ch iteration (CH = 0..3) of the attention main loop.
#define COMPUTE_CH(CH)                                                        \
  {                                                                           \
    bf16x8 Kf[8];                                                             \
    _Pragma("unroll") for (int t = 0; t < 8; ++t) Kf[t] =                     \
        *(const bf16x8*)&Ks[(((CH)*8 + t) * 16 + r) * 40 + g * 8];            \
    bf16x8 vb0[4], vb1[4];                                                    \
    _Pragma("unroll") for (int ks = 0; ks < 4; ++ks) {                        \
      vb0[ks] = *(const bf16x8*)&Vt[r * 520 + (CH)*128 + ks * 32 + g * 8];    \
      vb1[ks] =                                                               \
          *(const bf16x8*)&Vt[(16 + r) * 520 + (CH)*128 + ks * 32 + g * 8];   \
    }                                                                         \
    f32x4 sc[8];                                                              \
    _Pragma("unroll") for (int t = 0; t < 8; ++t) sc[t] =                     \
        __builtin_amdgcn_mfma_f32_16x16x32_bf16(Kf[t], qf, zero, 0, 0, 0);    \
    _Pragma("unroll") for (int ks = 0; ks < 4; ++ks) {                        \
      int bitidx = (CH)*8 + 2 * ks + ghalf;                                   \
      float f0 = ((mw[0] >> bitidx) & 1u) ? hiB : loB;                        \
      float f1 = ((mw[1] >> bitidx) & 1u) ? hiB : loB;                        \
      float f2 = ((mw[2] >> bitidx) & 1u) ? hiB : loB;                        \
      float f3 = ((mw[3] >> bitidx) & 1u) ? hiB : loB;                        \
      float f4 = ((mw[4] >> bitidx) & 1u) ? hiB : loB;                        \
      float f5 = ((mw[5] >> bitidx) & 1u) ? hiB : loB;                        \
      float f6 = ((mw[6] >> bitidx) & 1u) ? hiB : loB;                        \
      float f7 = ((mw[7] >> bitidx) & 1u) ? hiB : loB;                        \
      float p0 = vexp2(fmaf(sc[2 * ks][0], L2E, f0));                         \
      float p1 = vexp2(fmaf(sc[2 * ks][1], L2E, f1));                         \
      float p2 = vexp2(fmaf(sc[2 * ks][2], L2E, f2));                         \
      float p3 = vexp2(fmaf(sc[2 * ks][3], L2E, f3));                         \
      float p4 = vexp2(fmaf(sc[2 * ks + 1][0], L2E, f4));                     \
      float p5 = vexp2(fmaf(sc[2 * ks + 1][1], L2E, f5));                     \
      float p6 = vexp2(fmaf(sc[2 * ks + 1][2], L2E, f6));                     \
      float p7 = vexp2(fmaf(sc[2 * ks + 1][3], L2E, f7));                     \
      rsum += ((p0 + p1) + (p2 + p3)) + ((p4 + p5) + (p6 + p7));              \
      bf16x8 pa =                                                             \
          pack8(cvtpk(p0, p1), cvtpk(p2, p3), cvtpk(p4, p5), cvtpk(p6, p7));  \
      O0 = __builtin_amdgcn_mfma_f32_16x16x32_bf16(pa, vb0[ks], O0, 0, 0, 0); \
      O1 = __builtin_amdgcn_mfma_f32_16x16x32_bf16(pa, vb1[ks], O1, 0, 0, 0); \
    }                                                                         \
  }

// ---------------------------------------------------------------------------
// Kernel B: FUSED proj + attention (r18 geometry) with PIPELINED staging:
//   stage rows [0,256) -> barrier -> { stage rows [256,512) || compute
//   ch0,ch1 } -> barrier -> compute ch2,ch3.
// Second-half staging overlaps ch0/1 compute (disjoint LDS regions: Ks rows
// >=256, Vt cols >=256 vs reads of rows/cols <256). Straight-line phases.
// Grid = 512 (b, h, pg in {0,1}); 12 waves; one band per wave.
// ---------------------------------------------------------------------------
__global__ __launch_bounds__(768, 2) void attn_kernel(
    const float* __restrict__ query, const float* __restrict__ lanes,
    const short* __restrict__ WkT, const short* __restrict__ WvT,
    const float* __restrict__ bk, const float* __restrict__ bv,
    const unsigned int* __restrict__ maskr, const int* __restrict__ mi,
    short* __restrict__ out0b) {
  __shared__ short Ks[512 * 40];       // permuted rows, padded to 40 shorts
  __shared__ short Vt[32 * 520];       // d-rows padded to 520 shorts

  // XCD-affine decode: all 16 blocks of one b on one XCD (X/query L2 reuse)
  int i0 = blockIdx.x;
  int xcd = i0 & 7, widx = i0 >> 3;    // widx 0..63
  int b = xcd * 4 + (widx >> 4);
  int rem = widx & 15;
  int h = rem & 7, pg = rem >> 3;      // pg 0..1

  int tid = threadIdx.x;
  int w = tid >> 6, lane = tid & 63;   // w 0..11
  int r = lane & 15, g = lane >> 4;
  const f32x4 zero = {0.f, 0.f, 0.f, 0.f};

  // stage weights/biases (live across both stage phases)
  bf16x8 wk[2][2], wv[2][2];
#pragma unroll
  for (int dt = 0; dt < 2; ++dt)
#pragma unroll
    for (int c = 0; c < 2; ++c) {
      int f = h * 32 + dt * 16 + r;
      wk[dt][c] = *(const bf16x8*)&WkT[f * LF_ + c * 32 + g * 8];
      wv[dt][c] = *(const bf16x8*)&WvT[f * LF_ + c * 32 + g * 8];
    }
  float4 bk4[2];
  float bvf[2];
#pragma unroll
  for (int dt = 0; dt < 2; ++dt) {
    bk4[dt] = *(const float4*)&bk[h * 32 + dt * 16 + g * 4];
    bvf[dt] = bv[h * 32 + dt * 16 + r];
  }

  // ---- stage phase 1: rows [0,256) ----
  STAGE_RANGE(0, 16)

  // ---- per-wave band setup (ONE band per wave) ----
  int band = pg * 12 + w;              // 0..23
  int p = band >> 1, vb = (band & 1) << 4;
  const float* qp = &query[((p * B_ + b) * V_ + vb + r) * F_ + h * D_ + g * 8];
  float4 qa = *(const float4*)qp;
  float4 qq = *(const float4*)(qp + 4);
  bf16x8 qf = pack8(cvtpk(qa.x, qa.y), cvtpk(qa.z, qa.w),
                    cvtpk(qq.x, qq.y), cvtpk(qq.z, qq.w));
  float hiB = mi[b * V_ + vb + r] ? (-40.f * L2E) : -1.44269504e9f;
  const float loB = -1.44269504e9f;

  unsigned int mw[8];
#pragma unroll
  for (int q8 = 0; q8 < 8; ++q8) mw[q8] = maskr[b * 16 + ((g & 1) << 3) + q8];
  int ghalf = g >> 1;

  float rsum = 0.f;
  f32x4 O0 = zero, O1 = zero;

  __syncthreads();   // stage-1 visible

  // ---- stage phase 2 (rows [256,512)) overlapped with compute ch0,ch1 ----
  STAGE_RANGE(16, 32)
  COMPUTE_CH(0)
  COMPUTE_CH(1)

  __syncthreads();   // stage-2 visible

  COMPUTE_CH(2)
  COMPUTE_CH(3)

  // ================= epilogue (head-major out0b, line-disjoint) ============
  float rs = rsum;
  rs += __shfl_xor(rs, 16);
  rs += __shfl_xor(rs, 32);
  float invv = rs > 0.f ? 1.f / rs : 0.f;   // valid for v = r
#pragma unroll
  for (int j = 0; j < 4; ++j) {
    float inv = __shfl(invv, g * 4 + j);    // inv for v = g*4+j
    int v = vb + g * 4 + j;
    short* op = &out0b[(((h * P_ + p) * B_ + b) * V_ + v) * D_];
    op[r] = f2bf(__expf(O0[j] * inv));
    op[16 + r] = f2bf(__expf(O1[j] * inv));
  }
}

// ---------------------------------------------------------------------------
// Kernel C (MFMA): out = out0 @ Wc + bc. Swapped: C[f][row] = mfma(WcT, x).
// XCD-affine decode matching attn's out0b writer.
// ---------------------------------------------------------------------------
__global__ __launch_bounds__(256) void combine_kernel(
    const short* __restrict__ out0b, const short* __restrict__ WcT,
    const float* __restrict__ bc, float* __restrict__ out) {
  int blk = blockIdx.x;
  int xcd = blk & 7;
  int r3 = blk >> 3;              // 0..95
  int pgrp = r3 >> 3;             // 0..11
  int bblsb = (r3 >> 2) & 1;
  int ftq = r3 & 3;
  int bb = xcd * 2 + bblsb;       // 0..15
  int rblk = pgrp * 16 + bb;      // 0..191
  int tid = threadIdx.x;
  int w = tid >> 6, lane = tid & 63;
  int r = lane & 15, g = lane >> 4;
  int R = rblk * 64 + w * 16;

  bf16x8 xf[8];
#pragma unroll
  for (int c = 0; c < 8; ++c)
    xf[c] = *(const bf16x8*)&out0b[(c * (P_ * B_ * V_) + R + r) * D_ + g * 8];

  const f32x4 zero = {0.f, 0.f, 0.f, 0.f};
#pragma unroll
  for (int fi = 0; fi < 4; ++fi) {
    int ft = ftq * 4 + fi;
    f32x4 acc = zero;
#pragma unroll
    for (int c = 0; c < 8; ++c) {
      bf16x8 wf = *(const bf16x8*)&WcT[(ft * 16 + r) * F_ + c * 32 + g * 8];
      acc = __builtin_amdgcn_mfma_f32_16x16x32_bf16(wf, xf[c], acc, 0, 0, 0);
    }
    float4 bc4 = *(const float4*)&bc[ft * 16 + g * 4];
    float4 o;
    o.x = acc[0] + bc4.x;
    o.y = acc[1] + bc4.y;
    o.z = acc[2] + bc4.z;
    o.w = acc[3] + bc4.w;
    *(float4*)&out[(R + r) * F_ + ft * 16 + g * 4] = o;
  }
}

// ---------------------------------------------------------------------------
extern "C" void kernel_launch(void* const* d_in, const int* in_sizes, int n_in,
                              void* d_out, int out_size, void* d_ws, size_t ws_size,
                              hipStream_t stream) {
  const float* query = (const float*)d_in[0];
  const float* lanes = (const float*)d_in[1];
  const int* mask_input = (const int*)d_in[2];
  const int* mask_lanes = (const int*)d_in[3];
  const float* Wk = (const float*)d_in[4];
  const float* bk = (const float*)d_in[5];
  const float* Wv = (const float*)d_in[6];
  const float* bv = (const float*)d_in[7];
  const float* Wc = (const float*)d_in[8];
  const float* bc = (const float*)d_in[9];
  float* out = (float*)d_out;

  char* wp = (char*)d_ws;
  short* out0b = (short*)wp; wp += 6291456;   // H*P*B*V*D bf16 (head-major)
  short* WkT = (short*)wp;   wp += 32768;     // 256x64 bf16
  short* WvT = (short*)wp;   wp += 32768;
  short* WcT = (short*)wp;   wp += 131072;    // 256x256 bf16
  unsigned int* maskr = (unsigned int*)wp; wp += 2048;
  int* mi = (int*)wp;        wp += 4096;

  prep_kernel<<<54, 256, 0, stream>>>(Wk, Wv, Wc, mask_input, mask_lanes,
                                      WkT, WvT, WcT, maskr, mi);
  attn_kernel<<<B_ * H_ * 2, 768, 0, stream>>>(query, lanes, WkT, WvT, bk, bv,
                                               maskr, mi, out0b);
  combine_kernel<<<768, 256, 0, stream>>>(out0b, WcT, bc, out);
}

// Round 20
// 52.632 us; speedup vs baseline: 1.0547x; 1.0547x over previous
//
#include <hip/hip_runtime.h>
#include <cstdint>

#define P_ 12
#define B_ 32
#define V_ 32
#define F_ 256
#define S_ 32
#define NL_ 16
#define LF_ 64
#define T_ 20
#define H_ 8
#define D_ 32
#define L_ 512

typedef short bf16x8 __attribute__((ext_vector_type(8)));
typedef short bf16x4 __attribute__((ext_vector_type(4)));
typedef float f32x4 __attribute__((ext_vector_type(4)));

static __device__ __forceinline__ short f2bf(float f) {
  uint32_t u = __builtin_bit_cast(uint32_t, f);
  uint32_t r = u + 0x7FFFu + ((u >> 16) & 1u);  // RNE
  return (short)(r >> 16);
}

// packed f32x2 -> bf16x2 (RNE), 1 VALU op
static __device__ __forceinline__ uint32_t cvtpk(float lo, float hi) {
  uint32_t r;
  asm("v_cvt_pk_bf16_f32 %0, %1, %2" : "=v"(r) : "v"(lo), "v"(hi));
  return r;
}
static __device__ __forceinline__ bf16x8 pack8(uint32_t d0, uint32_t d1,
                                               uint32_t d2, uint32_t d3) {
  uint4 u = {d0, d1, d2, d3};
  return __builtin_bit_cast(bf16x8, u);
}
static __device__ __forceinline__ bf16x4 pack4(uint32_t d0, uint32_t d1) {
  uint2 u = {d0, d1};
  return __builtin_bit_cast(bf16x4, u);
}
static __device__ __forceinline__ float vexp2(float x) {
  float y;
  asm("v_exp_f32 %0, %1" : "=v"(y) : "v"(x));
  return y;
}
static __device__ __forceinline__ float vlog2(float x) {
  float y;
  asm("v_log_f32 %0, %1" : "=v"(y) : "v"(x));
  return y;
}

#define L2E 1.4426950408889634f
#define LN2 0.6931471805599453f

// ---------------------------------------------------------------------------
// Kernel P: prep = weight transpose/convert + mask precompute.
// ---------------------------------------------------------------------------
__global__ __launch_bounds__(256) void prep_kernel(
    const float* __restrict__ Wk, const float* __restrict__ Wv,
    const float* __restrict__ Wc,
    const int* __restrict__ mask_input, const int* __restrict__ mask_lanes,
    short* __restrict__ WkT, short* __restrict__ WvT, short* __restrict__ WcT,
    unsigned int* __restrict__ maskr, int* __restrict__ mi) {
  int t = blockIdx.x * 256 + threadIdx.x;
  if (t < 2048) {                 // WkT
    int f = t >> 3, k0 = (t & 7) * 8;
    bf16x8 o;
#pragma unroll
    for (int e = 0; e < 8; ++e) o[e] = f2bf(Wk[(k0 + e) * F_ + f]);
    *(bf16x8*)&WkT[f * LF_ + k0] = o;
  } else if (t < 4096) {          // WvT
    int i = t - 2048;
    int f = i >> 3, k0 = (i & 7) * 8;
    bf16x8 o;
#pragma unroll
    for (int e = 0; e < 8; ++e) o[e] = f2bf(Wv[(k0 + e) * F_ + f]);
    *(bf16x8*)&WvT[f * LF_ + k0] = o;
  } else if (t < 12288) {         // WcT
    int i = t - 4096;
    int f = i >> 5, k0 = (i & 31) * 8;
    bf16x8 o;
#pragma unroll
    for (int e = 0; e < 8; ++e) o[e] = f2bf(Wc[(k0 + e) * F_ + f]);
    *(bf16x8*)&WcT[f * F_ + k0] = o;
  } else if (t < 12800) {         // maskr: word = l&15, bit = l>>4
    int i = t - 12288;
    int b = i >> 4, r = i & 15;
    unsigned int bits = 0u;
    for (int lt = 0; lt < 32; ++lt)
      if (mask_lanes[(lt * B_ + b) * NL_ + r]) bits |= (1u << lt);
    maskr[i] = bits;
  } else if (t < 13824) {         // mi
    int i = t - 12800;
    int b = i >> 5, v = i & 31;
    int any = 0;
    for (int tt = 0; tt < T_; ++tt) any |= mask_input[(tt * B_ + b) * V_ + v];
    mi[i] = any ? 1 : 0;
  }
}

// ---------------------------------------------------------------------------
// Kernel B: FUSED proj + attention (r18-proven: 12 waves, one band/wave,
// whole grid co-resident at 2 blocks/CU). Epilogue exp via HW exp2.
// Grid = 512 (b, h, pg in {0,1}); stage: 32 16-row tiles strided over waves.
// ---------------------------------------------------------------------------
__global__ __launch_bounds__(768, 2) void attn_kernel(
    const float* __restrict__ query, const float* __restrict__ lanes,
    const short* __restrict__ WkT, const short* __restrict__ WvT,
    const float* __restrict__ bk, const float* __restrict__ bv,
    const unsigned int* __restrict__ maskr, const int* __restrict__ mi,
    short* __restrict__ out0b) {
  __shared__ short Ks[512 * 40];       // permuted rows, padded to 40 shorts
  __shared__ short Vt[32 * 520];       // d-rows padded to 520 shorts

  // XCD-affine decode: all 16 blocks of one b on one XCD (X/query L2 reuse)
  int i0 = blockIdx.x;
  int xcd = i0 & 7, widx = i0 >> 3;    // widx 0..63
  int b = xcd * 4 + (widx >> 4);
  int rem = widx & 15;
  int h = rem & 7, pg = rem >> 3;      // pg 0..1

  int tid = threadIdx.x;
  int w = tid >> 6, lane = tid & 63;   // w 0..11
  int r = lane & 15, g = lane >> 4;
  const f32x4 zero = {0.f, 0.f, 0.f, 0.f};

  // ================= stage phase: K/V projection via MFMA =================
  {
    bf16x8 wk[2][2], wv[2][2];
#pragma unroll
    for (int dt = 0; dt < 2; ++dt)
#pragma unroll
      for (int c = 0; c < 2; ++c) {
        int f = h * 32 + dt * 16 + r;
        wk[dt][c] = *(const bf16x8*)&WkT[f * LF_ + c * 32 + g * 8];
        wv[dt][c] = *(const bf16x8*)&WvT[f * LF_ + c * 32 + g * 8];
      }
    float4 bk4[2];
    float bvf[2];
#pragma unroll
    for (int dt = 0; dt < 2; ++dt) {
      bk4[dt] = *(const float4*)&bk[h * 32 + dt * 16 + g * 4];
      bvf[dt] = bv[h * 32 + dt * 16 + r];
    }

    // 32 16-row tiles strided over 12 waves (waves 0-7: 3 tiles, 8-11: 2)
    for (int t = w; t < 32; t += 12) {
      int l0 = t * 16;
      int l = l0 + r;
      int nl = l >> 5, s = l & 31;
      const float* xrow = &lanes[((s * B_ + b) * NL_ + nl) * LF_];
      bf16x8 xf[2];
#pragma unroll
      for (int c = 0; c < 2; ++c) {
        float4 a = *(const float4*)&xrow[c * 32 + g * 8];
        float4 q = *(const float4*)&xrow[c * 32 + g * 8 + 4];
        xf[c] = pack8(cvtpk(a.x, a.y), cvtpk(a.z, a.w),
                      cvtpk(q.x, q.y), cvtpk(q.z, q.w));
      }
      // permuted K row index: swap bits[4]<->[3:2] of (l&31)
      int sl = (l & ~31) | (((l >> 2) & 1) << 4) | (((l >> 3) & 3) << 2) | (l & 3);
#pragma unroll
      for (int dt = 0; dt < 2; ++dt) {
        f32x4 aK = __builtin_amdgcn_mfma_f32_16x16x32_bf16(wk[dt][0], xf[0], zero, 0, 0, 0);
        aK = __builtin_amdgcn_mfma_f32_16x16x32_bf16(wk[dt][1], xf[1], aK, 0, 0, 0);
        *(bf16x4*)&Ks[sl * 40 + dt * 16 + g * 4] =
            pack4(cvtpk(aK[0] + bk4[dt].x, aK[1] + bk4[dt].y),
                  cvtpk(aK[2] + bk4[dt].z, aK[3] + bk4[dt].w));
        f32x4 aV = __builtin_amdgcn_mfma_f32_16x16x32_bf16(xf[0], wv[dt][0], zero, 0, 0, 0);
        aV = __builtin_amdgcn_mfma_f32_16x16x32_bf16(xf[1], wv[dt][1], aV, 0, 0, 0);
        float ls[4];
#pragma unroll
        for (int reg = 0; reg < 4; ++reg) {
          float x = aV[reg] + bvf[dt];
          // log_sigmoid via HW: min(x,0) - ln2 * log2(1 + exp2(-|x|*log2e))
          float z = vexp2(fabsf(x) * -L2E);
          ls[reg] = fminf(x, 0.f) - vlog2(1.f + z) * LN2;
        }
        *(bf16x4*)&Vt[(dt * 16 + r) * 520 + l0 + g * 4] =
            pack4(cvtpk(ls[0], ls[1]), cvtpk(ls[2], ls[3]));
      }
    }
  }

  // ================= per-wave band setup (ONE band per wave) =================
  int band = pg * 12 + w;              // 0..23
  int p = band >> 1, vb = (band & 1) << 4;
  const float* qp = &query[((p * B_ + b) * V_ + vb + r) * F_ + h * D_ + g * 8];
  float4 qa = *(const float4*)qp;
  float4 qq = *(const float4*)(qp + 4);
  bf16x8 qf = pack8(cvtpk(qa.x, qa.y), cvtpk(qa.z, qa.w),
                    cvtpk(qq.x, qq.y), cvtpk(qq.z, qq.w));
  float hiB = mi[b * V_ + vb + r] ? (-40.f * L2E) : -1.44269504e9f;
  const float loB = -1.44269504e9f;

  unsigned int mw[8];
#pragma unroll
  for (int q8 = 0; q8 < 8; ++q8) mw[q8] = maskr[b * 16 + ((g & 1) << 3) + q8];
  int ghalf = g >> 1;

  float rsum = 0.f;
  f32x4 O0 = zero, O1 = zero;

  __syncthreads();

  // ================= attention main loop =================
#pragma unroll
  for (int ch = 0; ch < 4; ++ch) {
    bf16x8 Kf[8];
#pragma unroll
    for (int t = 0; t < 8; ++t)
      Kf[t] = *(const bf16x8*)&Ks[((ch * 8 + t) * 16 + r) * 40 + g * 8];

    bf16x8 vbuf[4][2];
#pragma unroll
    for (int ks = 0; ks < 4; ++ks) {
      vbuf[ks][0] = *(const bf16x8*)&Vt[r * 520 + ch * 128 + ks * 32 + g * 8];
      vbuf[ks][1] = *(const bf16x8*)&Vt[(16 + r) * 520 + ch * 128 + ks * 32 + g * 8];
    }

    f32x4 sc[8];
#pragma unroll
    for (int t = 0; t < 8; ++t)
      sc[t] = __builtin_amdgcn_mfma_f32_16x16x32_bf16(Kf[t], qf, zero, 0, 0, 0);

#pragma unroll
    for (int ks = 0; ks < 4; ++ks) {
      int bitidx = ch * 8 + 2 * ks + ghalf;
      float f0 = ((mw[0] >> bitidx) & 1u) ? hiB : loB;
      float f1 = ((mw[1] >> bitidx) & 1u) ? hiB : loB;
      float f2 = ((mw[2] >> bitidx) & 1u) ? hiB : loB;
      float f3 = ((mw[3] >> bitidx) & 1u) ? hiB : loB;
      float f4 = ((mw[4] >> bitidx) & 1u) ? hiB : loB;
      float f5 = ((mw[5] >> bitidx) & 1u) ? hiB : loB;
      float f6 = ((mw[6] >> bitidx) & 1u) ? hiB : loB;
      float f7 = ((mw[7] >> bitidx) & 1u) ? hiB : loB;
      float p0 = vexp2(fmaf(sc[2 * ks][0], L2E, f0));
      float p1 = vexp2(fmaf(sc[2 * ks][1], L2E, f1));
      float p2 = vexp2(fmaf(sc[2 * ks][2], L2E, f2));
      float p3 = vexp2(fmaf(sc[2 * ks][3], L2E, f3));
      float p4 = vexp2(fmaf(sc[2 * ks + 1][0], L2E, f4));
      float p5 = vexp2(fmaf(sc[2 * ks + 1][1], L2E, f5));
      float p6 = vexp2(fmaf(sc[2 * ks + 1][2], L2E, f6));
      float p7 = vexp2(fmaf(sc[2 * ks + 1][3], L2E, f7));
      rsum += ((p0 + p1) + (p2 + p3)) + ((p4 + p5) + (p6 + p7));
      bf16x8 pa = pack8(cvtpk(p0, p1), cvtpk(p2, p3),
                        cvtpk(p4, p5), cvtpk(p6, p7));
      O0 = __builtin_amdgcn_mfma_f32_16x16x32_bf16(pa, vbuf[ks][0], O0, 0, 0, 0);
      O1 = __builtin_amdgcn_mfma_f32_16x16x32_bf16(pa, vbuf[ks][1], O1, 0, 0, 0);
    }
  }

  // ===== epilogue (head-major out0b, line-disjoint); exp via HW exp2 =====
  float rs = rsum;
  rs += __shfl_xor(rs, 16);
  rs += __shfl_xor(rs, 32);
  float invv = (rs > 0.f ? 1.f / rs : 0.f) * L2E;   // exp2-domain reciprocal
#pragma unroll
  for (int j = 0; j < 4; ++j) {
    float inv = __shfl(invv, g * 4 + j);    // inv for v = g*4+j
    int v = vb + g * 4 + j;
    short* op = &out0b[(((h * P_ + p) * B_ + b) * V_ + v) * D_];
    op[r] = f2bf(vexp2(O0[j] * inv));
    op[16 + r] = f2bf(vexp2(O1[j] * inv));
  }
}

// ---------------------------------------------------------------------------
// Kernel C (MFMA): out = out0 @ Wc + bc. Swapped: C[f][row] = mfma(WcT, x).
// XCD-affine decode matching attn's out0b writer.
// ---------------------------------------------------------------------------
__global__ __launch_bounds__(256) void combine_kernel(
    const short* __restrict__ out0b, const short* __restrict__ WcT,
    const float* __restrict__ bc, float* __restrict__ out) {
  int blk = blockIdx.x;
  int xcd = blk & 7;
  int r3 = blk >> 3;              // 0..95
  int pgrp = r3 >> 3;             // 0..11
  int bblsb = (r3 >> 2) & 1;
  int ftq = r3 & 3;
  int bb = xcd * 2 + bblsb;       // 0..15
  int rblk = pgrp * 16 + bb;      // 0..191
  int tid = threadIdx.x;
  int w = tid >> 6, lane = tid & 63;
  int r = lane & 15, g = lane >> 4;
  int R = rblk * 64 + w * 16;

  bf16x8 xf[8];
#pragma unroll
  for (int c = 0; c < 8; ++c)
    xf[c] = *(const bf16x8*)&out0b[(c * (P_ * B_ * V_) + R + r) * D_ + g * 8];

  const f32x4 zero = {0.f, 0.f, 0.f, 0.f};
#pragma unroll
  for (int fi = 0; fi < 4; ++fi) {
    int ft = ftq * 4 + fi;
    f32x4 acc = zero;
#pragma unroll
    for (int c = 0; c < 8; ++c) {
      bf16x8 wf = *(const bf16x8*)&WcT[(ft * 16 + r) * F_ + c * 32 + g * 8];
      acc = __builtin_amdgcn_mfma_f32_16x16x32_bf16(wf, xf[c], acc, 0, 0, 0);
    }
    float4 bc4 = *(const float4*)&bc[ft * 16 + g * 4];
    float4 o;
    o.x = acc[0] + bc4.x;
    o.y = acc[1] + bc4.y;
    o.z = acc[2] + bc4.z;
    o.w = acc[3] + bc4.w;
    *(float4*)&out[(R + r) * F_ + ft * 16 + g * 4] = o;
  }
}

// ---------------------------------------------------------------------------
extern "C" void kernel_launch(void* const* d_in, const int* in_sizes, int n_in,
                              void* d_out, int out_size, void* d_ws, size_t ws_size,
                              hipStream_t stream) {
  const float* query = (const float*)d_in[0];
  const float* lanes = (const float*)d_in[1];
  const int* mask_input = (const int*)d_in[2];
  const int* mask_lanes = (const int*)d_in[3];
  const float* Wk = (const float*)d_in[4];
  const float* bk = (const float*)d_in[5];
  const float* Wv = (const float*)d_in[6];
  const float* bv = (const float*)d_in[7];
  const float* Wc = (const float*)d_in[8];
  const float* bc = (const float*)d_in[9];
  float* out = (float*)d_out;

  char* wp = (char*)d_ws;
  short* out0b = (short*)wp; wp += 6291456;   // H*P*B*V*D bf16 (head-major)
  short* WkT = (short*)wp;   wp += 32768;     // 256x64 bf16
  short* WvT = (short*)wp;   wp += 32768;
  short* WcT = (short*)wp;   wp += 131072;    // 256x256 bf16
  unsigned int* maskr = (unsigned int*)wp; wp += 2048;
  int* mi = (int*)wp;        wp += 4096;

  prep_kernel<<<54, 256, 0, stream>>>(Wk, Wv, Wc, mask_input, mask_lanes,
                                      WkT, WvT, WcT, maskr, mi);
  attn_kernel<<<B_ * H_ * 2, 768, 0, stream>>>(query, lanes, WkT, WvT, bk, bv,
                                               maskr, mi, out0b);
  combine_kernel<<<768, 256, 0, stream>>>(out0b, WcT, bc, out);
}

// Round 21
// 50.067 us; speedup vs baseline: 1.1087x; 1.0512x over previous
//
#include <hip/hip_runtime.h>
#include <cstdint>

#define P_ 12
#define B_ 32
#define V_ 32
#define F_ 256
#define S_ 32
#define NL_ 16
#define LF_ 64
#define T_ 20
#define H_ 8
#define D_ 32
#define L_ 512

typedef short bf16x8 __attribute__((ext_vector_type(8)));
typedef short bf16x4 __attribute__((ext_vector_type(4)));
typedef float f32x4 __attribute__((ext_vector_type(4)));

static __device__ __forceinline__ short f2bf(float f) {
  uint32_t u = __builtin_bit_cast(uint32_t, f);
  uint32_t r = u + 0x7FFFu + ((u >> 16) & 1u);  // RNE
  return (short)(r >> 16);
}

// packed f32x2 -> bf16x2 (RNE), 1 VALU op
static __device__ __forceinline__ uint32_t cvtpk(float lo, float hi) {
  uint32_t r;
  asm("v_cvt_pk_bf16_f32 %0, %1, %2" : "=v"(r) : "v"(lo), "v"(hi));
  return r;
}
static __device__ __forceinline__ bf16x8 pack8(uint32_t d0, uint32_t d1,
                                               uint32_t d2, uint32_t d3) {
  uint4 u = {d0, d1, d2, d3};
  return __builtin_bit_cast(bf16x8, u);
}
static __device__ __forceinline__ bf16x4 pack4(uint32_t d0, uint32_t d1) {
  uint2 u = {d0, d1};
  return __builtin_bit_cast(bf16x4, u);
}
static __device__ __forceinline__ float vexp2(float x) {
  float y;
  asm("v_exp_f32 %0, %1" : "=v"(y) : "v"(x));
  return y;
}
static __device__ __forceinline__ float vlog2(float x) {
  float y;
  asm("v_log_f32 %0, %1" : "=v"(y) : "v"(x));
  return y;
}

#define L2E 1.4426950408889634f
#define LN2 0.6931471805599453f
#define C40 (-40.0f * L2E)

// ---------------------------------------------------------------------------
// Kernel P: prep = weight transpose/convert + mask precompute.
// ---------------------------------------------------------------------------
__global__ __launch_bounds__(256) void prep_kernel(
    const float* __restrict__ Wk, const float* __restrict__ Wv,
    const float* __restrict__ Wc,
    const int* __restrict__ mask_input, const int* __restrict__ mask_lanes,
    short* __restrict__ WkT, short* __restrict__ WvT, short* __restrict__ WcT,
    unsigned int* __restrict__ maskr, int* __restrict__ mi) {
  int t = blockIdx.x * 256 + threadIdx.x;
  if (t < 2048) {                 // WkT
    int f = t >> 3, k0 = (t & 7) * 8;
    bf16x8 o;
#pragma unroll
    for (int e = 0; e < 8; ++e) o[e] = f2bf(Wk[(k0 + e) * F_ + f]);
    *(bf16x8*)&WkT[f * LF_ + k0] = o;
  } else if (t < 4096) {          // WvT
    int i = t - 2048;
    int f = i >> 3, k0 = (i & 7) * 8;
    bf16x8 o;
#pragma unroll
    for (int e = 0; e < 8; ++e) o[e] = f2bf(Wv[(k0 + e) * F_ + f]);
    *(bf16x8*)&WvT[f * LF_ + k0] = o;
  } else if (t < 12288) {         // WcT
    int i = t - 4096;
    int f = i >> 5, k0 = (i & 31) * 8;
    bf16x8 o;
#pragma unroll
    for (int e = 0; e < 8; ++e) o[e] = f2bf(Wc[(k0 + e) * F_ + f]);
    *(bf16x8*)&WcT[f * F_ + k0] = o;
  } else if (t < 12800) {         // maskr: word = l&15, bit = l>>4
    int i = t - 12288;
    int b = i >> 4, r = i & 15;
    unsigned int bits = 0u;
    for (int lt = 0; lt < 32; ++lt)
      if (mask_lanes[(lt * B_ + b) * NL_ + r]) bits |= (1u << lt);
    maskr[i] = bits;
  } else if (t < 13824) {         // mi
    int i = t - 12800;
    int b = i >> 5, v = i & 31;
    int any = 0;
    for (int tt = 0; tt < T_; ++tt) any |= mask_input[(tt * B_ + b) * V_ + v];
    mi[i] = any ? 1 : 0;
  }
}

// ---------------------------------------------------------------------------
// Kernel B: FUSED proj + attention (r18-proven geometry: 12 waves, one band
// per wave, whole grid co-resident at 2 blocks/CU).
// NEW: mask folded into the MFMA pipe --
//   * stage zeroes lsv columns of masked l (P*0 = 0 contribution to O)
//   * Msk[512] bf16 row; O2 = mfma(pa, mf) gives rsum[v] in every lane
//   * main loop softmax bias is one constant (-40*log2e): no selects/adds
// Grid = 512 (b, h, pg in {0,1}).
// ---------------------------------------------------------------------------
__global__ __launch_bounds__(768, 2) void attn_kernel(
    const float* __restrict__ query, const float* __restrict__ lanes,
    const short* __restrict__ WkT, const short* __restrict__ WvT,
    const float* __restrict__ bk, const float* __restrict__ bv,
    const unsigned int* __restrict__ maskr, const int* __restrict__ mi,
    short* __restrict__ out0b) {
  __shared__ short Ks[512 * 40];       // permuted rows, padded to 40 shorts
  __shared__ short Vt[32 * 520];       // d-rows padded to 520 shorts
  __shared__ short Msk[512];           // bf16 mask row (1.0 / 0.0 per l)

  // XCD-affine decode: all 16 blocks of one b on one XCD (X/query L2 reuse)
  int i0 = blockIdx.x;
  int xcd = i0 & 7, widx = i0 >> 3;    // widx 0..63
  int b = xcd * 4 + (widx >> 4);
  int rem = widx & 15;
  int h = rem & 7, pg = rem >> 3;      // pg 0..1

  int tid = threadIdx.x;
  int w = tid >> 6, lane = tid & 63;   // w 0..11
  int r = lane & 15, g = lane >> 4;
  const f32x4 zero = {0.f, 0.f, 0.f, 0.f};

  // ---- Msk fill: bf16 1.0/0.0 per l (same maskr mapping as stage) ----
  if (tid < 512) {
    unsigned int bits = maskr[b * 16 + (tid & 15)];
    Msk[tid] = ((bits >> (tid >> 4)) & 1u) ? (short)0x3F80 : (short)0;
  }

  // ================= stage phase: K/V projection via MFMA =================
  {
    bf16x8 wk[2][2], wv[2][2];
#pragma unroll
    for (int dt = 0; dt < 2; ++dt)
#pragma unroll
      for (int c = 0; c < 2; ++c) {
        int f = h * 32 + dt * 16 + r;
        wk[dt][c] = *(const bf16x8*)&WkT[f * LF_ + c * 32 + g * 8];
        wv[dt][c] = *(const bf16x8*)&WvT[f * LF_ + c * 32 + g * 8];
      }
    float4 bk4[2];
    float bvf[2];
#pragma unroll
    for (int dt = 0; dt < 2; ++dt) {
      bk4[dt] = *(const float4*)&bk[h * 32 + dt * 16 + g * 4];
      bvf[dt] = bv[h * 32 + dt * 16 + r];
    }
    // lane-mask words for the 4 l's this lane stores per tile (l&15 = g*4+reg)
    uint4 mwv = *(const uint4*)&maskr[b * 16 + g * 4];

    // 32 16-row tiles strided over 12 waves (waves 0-7: 3 tiles, 8-11: 2)
    for (int t = w; t < 32; t += 12) {
      int l0 = t * 16;
      int l = l0 + r;
      int nl = l >> 5, s = l & 31;
      const float* xrow = &lanes[((s * B_ + b) * NL_ + nl) * LF_];
      bf16x8 xf[2];
#pragma unroll
      for (int c = 0; c < 2; ++c) {
        float4 a = *(const float4*)&xrow[c * 32 + g * 8];
        float4 q = *(const float4*)&xrow[c * 32 + g * 8 + 4];
        xf[c] = pack8(cvtpk(a.x, a.y), cvtpk(a.z, a.w),
                      cvtpk(q.x, q.y), cvtpk(q.z, q.w));
      }
      // permuted K row index: swap bits[4]<->[3:2] of (l&31)
      int sl = (l & ~31) | (((l >> 2) & 1) << 4) | (((l >> 3) & 3) << 2) | (l & 3);
      // mask bits for the V store (l = l0 + g*4 + reg -> word g*4+reg, bit t)
      unsigned int m0 = (mwv.x >> t) & 1u;
      unsigned int m1 = (mwv.y >> t) & 1u;
      unsigned int m2 = (mwv.z >> t) & 1u;
      unsigned int m3 = (mwv.w >> t) & 1u;
#pragma unroll
      for (int dt = 0; dt < 2; ++dt) {
        f32x4 aK = __builtin_amdgcn_mfma_f32_16x16x32_bf16(wk[dt][0], xf[0], zero, 0, 0, 0);
        aK = __builtin_amdgcn_mfma_f32_16x16x32_bf16(wk[dt][1], xf[1], aK, 0, 0, 0);
        *(bf16x4*)&Ks[sl * 40 + dt * 16 + g * 4] =
            pack4(cvtpk(aK[0] + bk4[dt].x, aK[1] + bk4[dt].y),
                  cvtpk(aK[2] + bk4[dt].z, aK[3] + bk4[dt].w));
        f32x4 aV = __builtin_amdgcn_mfma_f32_16x16x32_bf16(xf[0], wv[dt][0], zero, 0, 0, 0);
        aV = __builtin_amdgcn_mfma_f32_16x16x32_bf16(xf[1], wv[dt][1], aV, 0, 0, 0);
        float ls[4];
#pragma unroll
        for (int reg = 0; reg < 4; ++reg) {
          float x = aV[reg] + bvf[dt];
          // log_sigmoid via HW: min(x,0) - ln2 * log2(1 + exp2(-|x|*log2e))
          float z = vexp2(fabsf(x) * -L2E);
          ls[reg] = fminf(x, 0.f) - vlog2(1.f + z) * LN2;
        }
        // zero masked-l columns (P*0 contribution; rsum handled by Msk MFMA)
        ls[0] = m0 ? ls[0] : 0.f;
        ls[1] = m1 ? ls[1] : 0.f;
        ls[2] = m2 ? ls[2] : 0.f;
        ls[3] = m3 ? ls[3] : 0.f;
        *(bf16x4*)&Vt[(dt * 16 + r) * 520 + l0 + g * 4] =
            pack4(cvtpk(ls[0], ls[1]), cvtpk(ls[2], ls[3]));
      }
    }
  }

  // ================= per-wave band setup (ONE band per wave) =================
  int band = pg * 12 + w;              // 0..23
  int p = band >> 1, vb = (band & 1) << 4;
  const float* qp = &query[((p * B_ + b) * V_ + vb + r) * F_ + h * D_ + g * 8];
  float4 qa = *(const float4*)qp;
  float4 qq = *(const float4*)(qp + 4);
  bf16x8 qf = pack8(cvtpk(qa.x, qa.y), cvtpk(qa.z, qa.w),
                    cvtpk(qq.x, qq.y), cvtpk(qq.z, qq.w));
  float mivf = mi[b * V_ + vb + r] ? 1.f : 0.f;   // for v = r

  f32x4 O0 = zero, O1 = zero, O2 = zero;

  __syncthreads();

  // ================= attention main loop =================
#pragma unroll
  for (int ch = 0; ch < 4; ++ch) {
    bf16x8 Kf[8];
#pragma unroll
    for (int t = 0; t < 8; ++t)
      Kf[t] = *(const bf16x8*)&Ks[((ch * 8 + t) * 16 + r) * 40 + g * 8];

    bf16x8 vbuf[4][2];
#pragma unroll
    for (int ks = 0; ks < 4; ++ks) {
      vbuf[ks][0] = *(const bf16x8*)&Vt[r * 520 + ch * 128 + ks * 32 + g * 8];
      vbuf[ks][1] = *(const bf16x8*)&Vt[(16 + r) * 520 + ch * 128 + ks * 32 + g * 8];
    }

    f32x4 sc[8];
#pragma unroll
    for (int t = 0; t < 8; ++t)
      sc[t] = __builtin_amdgcn_mfma_f32_16x16x32_bf16(Kf[t], qf, zero, 0, 0, 0);

#pragma unroll
    for (int ks = 0; ks < 4; ++ks) {
      float p0 = vexp2(fmaf(sc[2 * ks][0], L2E, C40));
      float p1 = vexp2(fmaf(sc[2 * ks][1], L2E, C40));
      float p2 = vexp2(fmaf(sc[2 * ks][2], L2E, C40));
      float p3 = vexp2(fmaf(sc[2 * ks][3], L2E, C40));
      float p4 = vexp2(fmaf(sc[2 * ks + 1][0], L2E, C40));
      float p5 = vexp2(fmaf(sc[2 * ks + 1][1], L2E, C40));
      float p6 = vexp2(fmaf(sc[2 * ks + 1][2], L2E, C40));
      float p7 = vexp2(fmaf(sc[2 * ks + 1][3], L2E, C40));
      bf16x8 pa = pack8(cvtpk(p0, p1), cvtpk(p2, p3),
                        cvtpk(p4, p5), cvtpk(p6, p7));
      // broadcast mask fragment: all 16 B-columns = m[l] -> O2[j] = rsum[v]
      bf16x8 mf = *(const bf16x8*)&Msk[ch * 128 + ks * 32 + g * 8];
      O0 = __builtin_amdgcn_mfma_f32_16x16x32_bf16(pa, vbuf[ks][0], O0, 0, 0, 0);
      O1 = __builtin_amdgcn_mfma_f32_16x16x32_bf16(pa, vbuf[ks][1], O1, 0, 0, 0);
      O2 = __builtin_amdgcn_mfma_f32_16x16x32_bf16(pa, mf, O2, 0, 0, 0);
    }
  }

  // ===== epilogue: O2[j] = rsum for v = g*4+j (every lane); exp2 out =====
#pragma unroll
  for (int j = 0; j < 4; ++j) {
    float mj = __shfl(mivf, g * 4 + j);     // mi for v = g*4+j
    float rs = O2[j];
    float inv = (rs > 0.f ? 1.f / rs : 0.f) * L2E * mj;
    int v = vb + g * 4 + j;
    short* op = &out0b[(((h * P_ + p) * B_ + b) * V_ + v) * D_];
    op[r] = f2bf(vexp2(O0[j] * inv));
    op[16 + r] = f2bf(vexp2(O1[j] * inv));
  }
}

// ---------------------------------------------------------------------------
// Kernel C (MFMA): out = out0 @ Wc + bc. Swapped: C[f][row] = mfma(WcT, x).
// XCD-affine decode matching attn's out0b writer.
// ---------------------------------------------------------------------------
__global__ __launch_bounds__(256) void combine_kernel(
    const short* __restrict__ out0b, const short* __restrict__ WcT,
    const float* __restrict__ bc, float* __restrict__ out) {
  int blk = blockIdx.x;
  int xcd = blk & 7;
  int r3 = blk >> 3;              // 0..95
  int pgrp = r3 >> 3;             // 0..11
  int bblsb = (r3 >> 2) & 1;
  int ftq = r3 & 3;
  int bb = xcd * 2 + bblsb;       // 0..15
  int rblk = pgrp * 16 + bb;      // 0..191
  int tid = threadIdx.x;
  int w = tid >> 6, lane = tid & 63;
  int r = lane & 15, g = lane >> 4;
  int R = rblk * 64 + w * 16;

  bf16x8 xf[8];
#pragma unroll
  for (int c = 0; c < 8; ++c)
    xf[c] = *(const bf16x8*)&out0b[(c * (P_ * B_ * V_) + R + r) * D_ + g * 8];

  const f32x4 zero = {0.f, 0.f, 0.f, 0.f};
#pragma unroll
  for (int fi = 0; fi < 4; ++fi) {
    int ft = ftq * 4 + fi;
    f32x4 acc = zero;
#pragma unroll
    for (int c = 0; c < 8; ++c) {
      bf16x8 wf = *(const bf16x8*)&WcT[(ft * 16 + r) * F_ + c * 32 + g * 8];
      acc = __builtin_amdgcn_mfma_f32_16x16x32_bf16(wf, xf[c], acc, 0, 0, 0);
    }
    float4 bc4 = *(const float4*)&bc[ft * 16 + g * 4];
    float4 o;
    o.x = acc[0] + bc4.x;
    o.y = acc[1] + bc4.y;
    o.z = acc[2] + bc4.z;
    o.w = acc[3] + bc4.w;
    *(float4*)&out[(R + r) * F_ + ft * 16 + g * 4] = o;
  }
}

// ---------------------------------------------------------------------------
extern "C" void kernel_launch(void* const* d_in, const int* in_sizes, int n_in,
                              void* d_out, int out_size, void* d_ws, size_t ws_size,
                              hipStream_t stream) {
  const float* query = (const float*)d_in[0];
  const float* lanes = (const float*)d_in[1];
  const int* mask_input = (const int*)d_in[2];
  const int* mask_lanes = (const int*)d_in[3];
  const float* Wk = (const float*)d_in[4];
  const float* bk = (const float*)d_in[5];
  const float* Wv = (const float*)d_in[6];
  const float* bv = (const float*)d_in[7];
  const float* Wc = (const float*)d_in[8];
  const float* bc = (const float*)d_in[9];
  float* out = (float*)d_out;

  char* wp = (char*)d_ws;
  short* out0b = (short*)wp; wp += 6291456;   // H*P*B*V*D bf16 (head-major)
  short* WkT = (short*)wp;   wp += 32768;     // 256x64 bf16
  short* WvT = (short*)wp;   wp += 32768;
  short* WcT = (short*)wp;   wp += 131072;    // 256x256 bf16
  unsigned int* maskr = (unsigned int*)wp; wp += 2048;
  int* mi = (int*)wp;        wp += 4096;

  prep_kernel<<<54, 256, 0, stream>>>(Wk, Wv, Wc, mask_input, mask_lanes,
                                      WkT, WvT, WcT, maskr, mi);
  attn_kernel<<<B_ * H_ * 2, 768, 0, stream>>>(query, lanes, WkT, WvT, bk, bv,
                                               maskr, mi, out0b);
  combine_kernel<<<768, 256, 0, stream>>>(out0b, WcT, bc, out);
}